// Round 1
// 615.403 us; speedup vs baseline: 1.0672x; 1.0672x over previous
//
#include <hip/hip_runtime.h>
#include <math.h>

#define N_NODES 100000
#define N_EDGES 1600000
#define IN_DIM  512
#define OUT_DIM 128

// ---------------- ws layout (float offsets) ----------------
#define OFF_S1    0        // 512  (s1 | s2 contiguous: 1024 floats)
#define OFF_S2    512      // 512
#define OFF_M     1024     // 256: m[2][128]
#define OFF_U     1280     // 256: u[2][128]
#define OFF_WV    1536     // 1024: w12[512] | w21[512]
#define OFF_ALPHA 2560     // 2
#define OFF_PA    4096     // float2[N]: {p_f2, p_s2}   (graph2 table)
#define OFF_PB    204096   // float2[N]: {p_f1, p_s1}   (graph1 table)
#define OFF_DEGR  404096   // int[2][100000] reduced degrees
#define OFF_BUF   604096   // degbuf: Cd*200000 ints -> dead after k_degred, then
                           // pbuf: 1024*1024 floats (aliases degbuf) -> dead after k_sred
                           // scbuf: Cs*400000 floats at OFF_BUF + Cd*200000

// 32 KiB LDS partitions -> 4 blocks/CU (512 thr each) = 32 waves/CU
#define P_SC   4096        // nodes per scatter partition (2 * 4096 * 4B = 32KB LDS)
#define NP_SC  25          // ceil(100000/4096)
#define P_D    8192        // nodes per degree partition (8192 * 4B = 32KB LDS)
#define NP_D   13          // ceil(100000/8192)
#define WSUM_NBLK 1024

// bijective hardware-block -> logical-id swizzle: blocks with the same
// hardware residue mod 8 (= same XCD under round-robin dispatch) get a
// CONTIGUOUS logical range, so logically-adjacent blocks share an XCD's L2.
__device__ __forceinline__ int xcd_swz(int bx, int nwg) {
    const int q = nwg >> 3, r = nwg & 7;
    const int x = bx & 7, i = bx >> 3;
    return (x < r ? x * (q + 1) : r * (q + 1) + (x - r) * q) + i;
}

__global__ void k_zero(float* __restrict__ p, long n) {
    long i = (long)blockIdx.x * blockDim.x + threadIdx.x;
    long stride = (long)gridDim.x * blockDim.x;
    for (long j = i; j < n; j += stride) p[j] = 0.0f;
}

// ---- binned degree histogram: 1-D grid NP_D*Cd*2, 512 thr, 32KB LDS, no global atomics.
// Swizzled so all NP_D partition blocks of one (g,c) edge-chunk live on one XCD:
// the chunk is fetched from HBM once per XCD, re-scans hit L2.
__global__ __launch_bounds__(512) void k_deg_b(const int* __restrict__ src1,
                                               const int* __restrict__ src2,
                                               int* __restrict__ degbuf, int Cd) {
    __shared__ int bins[P_D];
    const int nwg  = NP_D * Cd * 2;
    const int l    = xcd_swz(blockIdx.x, nwg);
    const int part = l % NP_D;
    const int grp  = l / NP_D;        // g*Cd + c
    const int c    = grp % Cd;
    const int g    = grp / Cd;
    const int tid  = threadIdx.x;
    const int base = part * P_D;
    const int4* srcv = (const int4*)(g ? src2 : src1);
    for (int i = tid; i < P_D; i += 512) bins[i] = 0;
    __syncthreads();
    const long E4 = N_EDGES / 4;
    const long s4 = ((long)c * E4) / Cd;
    const long e4 = ((long)(c + 1) * E4) / Cd;
#pragma unroll 2
    for (long i = s4 + tid; i < e4; i += 512) {
        int4 s = srcv[i];
        unsigned l0 = (unsigned)(s.x - base), l1 = (unsigned)(s.y - base);
        unsigned l2 = (unsigned)(s.z - base), l3 = (unsigned)(s.w - base);
        if (l0 < P_D) atomicAdd(&bins[l0], 1);
        if (l1 < P_D) atomicAdd(&bins[l1], 1);
        if (l2 < P_D) atomicAdd(&bins[l2], 1);
        if (l3 < P_D) atomicAdd(&bins[l3], 1);
    }
    __syncthreads();
    const int valid = min(P_D, N_NODES - base);
    int* o = degbuf + (size_t)c * 200000 + (size_t)g * 100000 + base;
    for (int li = tid; li < valid; li += 512) o[li] = bins[li];
}

__global__ void k_degred(const int* __restrict__ degbuf, int* __restrict__ degr, int Cd) {
    int j = blockIdx.x * blockDim.x + threadIdx.x;
    if (j < 200000) {
        int acc = 0;
        for (int c = 0; c < Cd; ++c) acc += degbuf[(size_t)c * 200000 + j];
        degr[j] = acc;
    }
}

// ---- partial-sum wsum: contiguous chunks, 4-row unroll, plain float4 stores.
// Block b writes pbuf[b*1024 + 0..511] = sum deg1[v]*feat[v][:], [512..1023] for deg2.
__global__ __launch_bounds__(128) void k_wsum_p(const float* __restrict__ feat,
                                                const int* __restrict__ degr,
                                                float* __restrict__ pbuf) {
    const int t = threadIdx.x;
    const int k = 4 * t;
    const int chunk = (N_NODES + WSUM_NBLK - 1) / WSUM_NBLK;   // 98
    const int v0 = blockIdx.x * chunk;
    const int v1 = min(v0 + chunk, N_NODES);
    float4 a1 = {0.f, 0.f, 0.f, 0.f};
    float4 a2 = {0.f, 0.f, 0.f, 0.f};
    const float* fp = feat + (size_t)v0 * IN_DIM + k;
    int v = v0;
    for (; v + 4 <= v1; v += 4, fp += 4 * IN_DIM) {
        float4 f0 = *(const float4*)(fp);
        float4 f1 = *(const float4*)(fp + IN_DIM);
        float4 f2 = *(const float4*)(fp + 2 * IN_DIM);
        float4 f3 = *(const float4*)(fp + 3 * IN_DIM);
        float d10 = (float)degr[v],     d20 = (float)degr[100000 + v];
        float d11 = (float)degr[v + 1], d21 = (float)degr[100000 + v + 1];
        float d12 = (float)degr[v + 2], d22 = (float)degr[100000 + v + 2];
        float d13 = (float)degr[v + 3], d23 = (float)degr[100000 + v + 3];
        a1.x += d10 * f0.x + d11 * f1.x + d12 * f2.x + d13 * f3.x;
        a1.y += d10 * f0.y + d11 * f1.y + d12 * f2.y + d13 * f3.y;
        a1.z += d10 * f0.z + d11 * f1.z + d12 * f2.z + d13 * f3.z;
        a1.w += d10 * f0.w + d11 * f1.w + d12 * f2.w + d13 * f3.w;
        a2.x += d20 * f0.x + d21 * f1.x + d22 * f2.x + d23 * f3.x;
        a2.y += d20 * f0.y + d21 * f1.y + d22 * f2.y + d23 * f3.y;
        a2.z += d20 * f0.z + d21 * f1.z + d22 * f2.z + d23 * f3.z;
        a2.w += d20 * f0.w + d21 * f1.w + d22 * f2.w + d23 * f3.w;
    }
    for (; v < v1; ++v, fp += IN_DIM) {
        float4 f = *(const float4*)(fp);
        float d1 = (float)degr[v], d2 = (float)degr[100000 + v];
        a1.x += d1 * f.x; a1.y += d1 * f.y; a1.z += d1 * f.z; a1.w += d1 * f.w;
        a2.x += d2 * f.x; a2.y += d2 * f.y; a2.z += d2 * f.z; a2.w += d2 * f.w;
    }
    float* o = pbuf + (size_t)blockIdx.x * 1024;
    *(float4*)(o + k) = a1;           // zeros for empty blocks (pbuf is poisoned!)
    *(float4*)(o + 512 + k) = a2;
}

// grid (4,16) x 256: dim d = bx*256+t; sum 64 block-partials; 16-deep atomic chain only.
__global__ void k_sred(const float* __restrict__ pbuf, float* __restrict__ s) {
    const int d = blockIdx.x * 256 + threadIdx.x;
    const int b0 = blockIdx.y * 64;
    float acc = 0.f;
#pragma unroll 8
    for (int b = 0; b < 64; ++b) acc += pbuf[(size_t)(b0 + b) * 1024 + d];
    atomicAdd(&s[d], acc);
}

__global__ void k_gemv_m(const float* __restrict__ ws, const float* __restrict__ W1,
                         const float* __restrict__ W2, float* __restrict__ m) {
    const int mat = blockIdx.y;
    const float* W = mat ? W2 : W1;
    const float* s = ws + (mat ? OFF_S2 : OFF_S1);
    const int t = threadIdx.x;
    const int k0 = blockIdx.x * 32;
    float acc = 0.f;
#pragma unroll 8
    for (int j = 0; j < 32; ++j)
        acc += s[k0 + j] * W[(k0 + j) * OUT_DIM + t];
    atomicAdd(&m[mat * OUT_DIM + t], acc);
}

__global__ void k_u(float* __restrict__ ws, const float* __restrict__ b1,
                    const float* __restrict__ b2, const float* __restrict__ Wb,
                    const float* __restrict__ bb) {
    __shared__ float c[OUT_DIM];
    __shared__ float red[128];
    const int mat = blockIdx.x;
    const int t = threadIdx.x;
    const float* b = mat ? b2 : b1;
    float mv = ws[OFF_M + mat * OUT_DIM + t] * (1.0f / N_NODES) + b[t];
    c[t] = 1.0f / (1.0f + expf(-mv));
    __syncthreads();
    float acc = 0.f;
    const float4* wr = (const float4*)(Wb + t * OUT_DIM);
#pragma unroll 8
    for (int j = 0; j < OUT_DIM / 4; ++j) {
        float4 w = wr[j];
        acc += w.x * c[4 * j] + w.y * c[4 * j + 1] + w.z * c[4 * j + 2] + w.w * c[4 * j + 3];
    }
    ws[OFF_U + mat * OUT_DIM + t] = acc;   // mat0: u1, mat1: u2
    const float* bo = mat ? b1 : b2;       // alpha0 = b2.u1+bb ; alpha1 = b1.u2+bb
    red[t] = bo[t] * acc;
    __syncthreads();
    for (int s = 64; s > 0; s >>= 1) {
        if (t < s) red[t] += red[t + s];
        __syncthreads();
    }
    if (t == 0) ws[OFF_ALPHA + mat] = red[0] + bb[0];
}

__global__ void k_w(const float* __restrict__ ws, const float* __restrict__ W1,
                    const float* __restrict__ W2, float* __restrict__ wv) {
    const int wid = (blockIdx.x * blockDim.x + threadIdx.x) >> 6;
    const int lane = threadIdx.x & 63;
    const int mat = wid >> 9;
    const int k = wid & 511;
    const float* W = mat ? W2 : W1;
    const float* u = ws + OFF_U + (mat ? 0 : OUT_DIM);  // mat0 needs u2, mat1 needs u1
    float2 w = *(const float2*)(W + k * OUT_DIM + 2 * lane);
    float2 uu = *(const float2*)(u + 2 * lane);
    float acc = w.x * uu.x + w.y * uu.y;
#pragma unroll
    for (int off = 32; off > 0; off >>= 1) acc += __shfl_down(acc, off);
    if (lane == 0) wv[mat * IN_DIM + k] = acc;
}

__device__ __forceinline__ float dot8(float4 a, float4 b, float4 wa, float4 wb) {
    return a.x * wa.x + a.y * wa.y + a.z * wa.z + a.w * wa.w
         + b.x * wb.x + b.y * wb.y + b.z * wb.z + b.w * wb.w;
}

__global__ void k_proj(const float* __restrict__ feat, const float* __restrict__ shuf,
                       const float* __restrict__ ws, float2* __restrict__ pA,
                       float2* __restrict__ pB) {
    const int lane = threadIdx.x & 63;
    const int gw = (blockIdx.x * blockDim.x + threadIdx.x) >> 6;
    const int nw = (gridDim.x * blockDim.x) >> 6;
    const int kA = 4 * lane;
    const int kB = 256 + 4 * lane;
    const float* wv = ws + OFF_WV;
    const float4 w12a = *(const float4*)(wv + kA);
    const float4 w12b = *(const float4*)(wv + kB);
    const float4 w21a = *(const float4*)(wv + IN_DIM + kA);
    const float4 w21b = *(const float4*)(wv + IN_DIM + kB);
    for (int v = gw; v < N_NODES; v += nw) {
        const float* rf = feat + (size_t)v * IN_DIM;
        float4 fa = *(const float4*)(rf + kA);
        float4 fb = *(const float4*)(rf + kB);
        const float* rs = shuf + (size_t)v * IN_DIM;
        float4 sa = *(const float4*)(rs + kA);
        float4 sb = *(const float4*)(rs + kB);
        float d12f = dot8(fa, fb, w12a, w12b);
        float d21f = dot8(fa, fb, w21a, w21b);
        float d12s = dot8(sa, sb, w12a, w12b);
        float d21s = dot8(sa, sb, w21a, w21b);
#pragma unroll
        for (int off = 32; off > 0; off >>= 1) {
            d12f += __shfl_down(d12f, off);
            d21f += __shfl_down(d21f, off);
            d12s += __shfl_down(d12s, off);
            d21s += __shfl_down(d21s, off);
        }
        if (lane == 0) {
            pA[v] = make_float2(d21f, d21s);   // {p_f2, p_s2}
            pB[v] = make_float2(d12f, d12s);   // {p_f1, p_s1}
        }
    }
}

// ---- binned scatter: 1-D grid NP_SC*Cs*2, 512 thr, 32KB LDS, no global atomics.
// Swizzled so all NP_SC partition blocks of one (g,c) edge-chunk live on one XCD:
// dst/src chunk and the 800KB gather table become L2-resident (per-XCD working set
// at Cs=16: 4 chunks x 800KB + 1 table = ~4MB = L2 size). 4 blocks/CU occupancy.
__global__ __launch_bounds__(512) void k_sc_b(const int* __restrict__ src1,
                                              const int* __restrict__ dst1,
                                              const int* __restrict__ src2,
                                              const int* __restrict__ dst2,
                                              const float2* __restrict__ pA,
                                              const float2* __restrict__ pB,
                                              float* __restrict__ scbuf, int Cs) {
    __shared__ float bins[2 * P_SC];
    const int nwg  = NP_SC * Cs * 2;
    const int l    = xcd_swz(blockIdx.x, nwg);
    const int part = l % NP_SC;
    const int grp  = l / NP_SC;       // g*Cs + c
    const int c    = grp % Cs;
    const int g    = grp / Cs;
    const int tid  = threadIdx.x;
    const int base = part * P_SC;
    const int4* dstv = (const int4*)(g ? dst2 : dst1);
    const int4* srcv = (const int4*)(g ? src2 : src1);
    const float2* tab = g ? pA : pB;
    for (int i = tid; i < 2 * P_SC; i += 512) bins[i] = 0.f;
    __syncthreads();
    const long E4 = N_EDGES / 4;
    const long s4 = ((long)c * E4) / Cs;
    const long e4 = ((long)(c + 1) * E4) / Cs;
#pragma unroll 2
    for (long i = s4 + tid; i < e4; i += 512) {
        int4 d = dstv[i];
        unsigned l0 = (unsigned)(d.x - base), l1 = (unsigned)(d.y - base);
        unsigned l2 = (unsigned)(d.z - base), l3 = (unsigned)(d.w - base);
        bool h0 = l0 < P_SC, h1 = l1 < P_SC, h2 = l2 < P_SC, h3 = l3 < P_SC;
        if (h0 | h1 | h2 | h3) {
            int4 s = srcv[i];
            if (h0) { float2 p = tab[s.x]; atomicAdd(&bins[l0], p.x); atomicAdd(&bins[P_SC + l0], p.y); }
            if (h1) { float2 p = tab[s.y]; atomicAdd(&bins[l1], p.x); atomicAdd(&bins[P_SC + l1], p.y); }
            if (h2) { float2 p = tab[s.z]; atomicAdd(&bins[l2], p.x); atomicAdd(&bins[P_SC + l2], p.y); }
            if (h3) { float2 p = tab[s.w]; atomicAdd(&bins[l3], p.x); atomicAdd(&bins[P_SC + l3], p.y); }
        }
    }
    __syncthreads();
    const int valid = min(P_SC, N_NODES - base);
    const int secA = g ? 0 : 1;
    const int secB = g ? 2 : 3;
    float* oA = scbuf + ((size_t)c * 4 + secA) * 100000 + base;
    float* oB = scbuf + ((size_t)c * 4 + secB) * 100000 + base;
    for (int li = tid; li < valid; li += 512) {
        oA[li] = bins[li];
        oB[li] = bins[P_SC + li];
    }
}

__global__ void k_final(const float* __restrict__ scbuf, const float* __restrict__ ws,
                        float* __restrict__ out, int Cs) {
    int i = blockIdx.x * blockDim.x + threadIdx.x;
    if (i < 4 * N_NODES) {
        int sec = i / N_NODES;
        int v = i - sec * N_NODES;
        float t = 0.f;
        for (int c = 0; c < Cs; ++c) t += scbuf[((size_t)c * 4 + sec) * 100000 + v];
        out[i] = ws[OFF_ALPHA + (sec & 1)] + t;
    }
}

// ---------------- fallbacks (small ws) ----------------
__global__ void k_wsum_atomic(const float* __restrict__ feat, const int* __restrict__ degr,
                              float* __restrict__ s1, float* __restrict__ s2) {
    const int k = 4 * threadIdx.x;
    float4 a1 = {0.f, 0.f, 0.f, 0.f};
    float4 a2 = {0.f, 0.f, 0.f, 0.f};
    for (int v = blockIdx.x; v < N_NODES; v += gridDim.x) {
        float d1 = (float)degr[v];
        float d2 = (float)degr[100000 + v];
        float4 f = *reinterpret_cast<const float4*>(feat + (size_t)v * IN_DIM + k);
        a1.x += d1 * f.x; a1.y += d1 * f.y; a1.z += d1 * f.z; a1.w += d1 * f.w;
        a2.x += d2 * f.x; a2.y += d2 * f.y; a2.z += d2 * f.z; a2.w += d2 * f.w;
    }
    atomicAdd(&s1[k],     a1.x); atomicAdd(&s1[k + 1], a1.y);
    atomicAdd(&s1[k + 2], a1.z); atomicAdd(&s1[k + 3], a1.w);
    atomicAdd(&s2[k],     a2.x); atomicAdd(&s2[k + 1], a2.y);
    atomicAdd(&s2[k + 2], a2.z); atomicAdd(&s2[k + 3], a2.w);
}

__global__ void k_deg_direct(const int* __restrict__ src1, const int* __restrict__ src2,
                             int* __restrict__ degr) {
    int i = blockIdx.x * blockDim.x + threadIdx.x;
    if (i < N_EDGES) {
        atomicAdd(&degr[src1[i]], 1);
        atomicAdd(&degr[100000 + src2[i]], 1);
    }
}

__global__ void k_init(float* __restrict__ out, const float* __restrict__ ws) {
    int i = blockIdx.x * blockDim.x + threadIdx.x;
    if (i < 4 * N_NODES) {
        int sec = i / N_NODES;
        out[i] = ws[OFF_ALPHA + (sec & 1)];
    }
}

__global__ void k_scatter_direct(const int* __restrict__ src1, const int* __restrict__ dst1,
                                 const int* __restrict__ src2, const int* __restrict__ dst2,
                                 const float2* __restrict__ pA, const float2* __restrict__ pB,
                                 float* __restrict__ out) {
    int i = blockIdx.x * blockDim.x + threadIdx.x;
    if (i < N_EDGES) {
        int s1 = src1[i], d1 = dst1[i];
        int s2 = src2[i], d2 = dst2[i];
        float2 a = pA[s2];
        float2 b = pB[s1];
        atomicAdd(&out[d2],                 a.x);
        atomicAdd(&out[2 * N_NODES + d2],   a.y);
        atomicAdd(&out[N_NODES + d1],       b.x);
        atomicAdd(&out[3 * N_NODES + d1],   b.y);
    }
}

extern "C" void kernel_launch(void* const* d_in, const int* in_sizes, int n_in,
                              void* d_out, int out_size, void* d_ws, size_t ws_size,
                              hipStream_t stream) {
    const float* feat = (const float*)d_in[0];
    const float* shuf = (const float*)d_in[1];
    const int* src1 = (const int*)d_in[2];
    const int* dst1 = (const int*)d_in[3];
    const int* src2 = (const int*)d_in[4];
    const int* dst2 = (const int*)d_in[5];
    const float* W1 = (const float*)d_in[6];
    const float* b1 = (const float*)d_in[7];
    const float* W2 = (const float*)d_in[8];
    const float* b2 = (const float*)d_in[9];
    const float* Wb = (const float*)d_in[10];
    const float* bb = (const float*)d_in[11];
    float* out = (float*)d_out;

    float* wsf = (float*)d_ws;
    float2* pA = (float2*)(wsf + OFF_PA);
    float2* pB = (float2*)(wsf + OFF_PB);
    int* degr = (int*)(wsf + OFF_DEGR);

    long availf = (long)(ws_size / 4);
    long budget = availf - OFF_BUF;
    int Cd = 0, Cs = 0;
    if (budget >= 600000) {
        Cs = (int)((budget / 2) / 400000); if (Cs > 16) Cs = 16; if (Cs < 1) Cs = 1;
        Cd = (int)((budget - (long)Cs * 400000) / 200000); if (Cd > 16) Cd = 16; if (Cd < 1) Cd = 1;
    }
    const bool pb_ok = (budget >= 1048576);   // pbuf aliases the (dead) degbuf region

    if (Cd >= 1) {
        int* degbuf = (int*)(wsf + OFF_BUF);
        float* pbuf = wsf + OFF_BUF;          // alias: degbuf dead after k_degred
        float* scbuf = wsf + OFF_BUF + (long)Cd * 200000;
        k_zero<<<2, 512, 0, stream>>>(wsf, 1280);   // s1,s2,m accumulators
        k_deg_b<<<NP_D * Cd * 2, 512, 0, stream>>>(src1, src2, degbuf, Cd);
        k_degred<<<(200000 + 255) / 256, 256, 0, stream>>>(degbuf, degr, Cd);
        if (pb_ok) {
            k_wsum_p<<<WSUM_NBLK, 128, 0, stream>>>(feat, degr, pbuf);
            k_sred<<<dim3(4, 16), 256, 0, stream>>>(pbuf, wsf + OFF_S1);
        } else {
            k_wsum_atomic<<<2048, 128, 0, stream>>>(feat, degr, wsf + OFF_S1, wsf + OFF_S2);
        }
        k_gemv_m<<<dim3(16, 2), 128, 0, stream>>>(wsf, W1, W2, wsf + OFF_M);
        k_u<<<2, 128, 0, stream>>>(wsf, b1, b2, Wb, bb);
        k_w<<<256, 256, 0, stream>>>(wsf, W1, W2, wsf + OFF_WV);
        k_proj<<<8192, 256, 0, stream>>>(feat, shuf, wsf, pA, pB);
        k_sc_b<<<NP_SC * Cs * 2, 512, 0, stream>>>(src1, dst1, src2, dst2, pA, pB, scbuf, Cs);
        k_final<<<(4 * N_NODES + 255) / 256, 256, 0, stream>>>(scbuf, wsf, out, Cs);
    } else {
        k_zero<<<2, 512, 0, stream>>>(wsf, 1280);
        k_zero<<<256, 256, 0, stream>>>((float*)degr, 200000);
        k_deg_direct<<<(N_EDGES + 255) / 256, 256, 0, stream>>>(src1, src2, degr);
        k_wsum_atomic<<<2048, 128, 0, stream>>>(feat, degr, wsf + OFF_S1, wsf + OFF_S2);
        k_gemv_m<<<dim3(16, 2), 128, 0, stream>>>(wsf, W1, W2, wsf + OFF_M);
        k_u<<<2, 128, 0, stream>>>(wsf, b1, b2, Wb, bb);
        k_w<<<256, 256, 0, stream>>>(wsf, W1, W2, wsf + OFF_WV);
        k_proj<<<8192, 256, 0, stream>>>(feat, shuf, wsf, pA, pB);
        k_init<<<(4 * N_NODES + 255) / 256, 256, 0, stream>>>(out, wsf);
        k_scatter_direct<<<(N_EDGES + 255) / 256, 256, 0, stream>>>(src1, dst1, src2, dst2, pA, pB, out);
    }
}

// Round 2
// 583.314 us; speedup vs baseline: 1.1259x; 1.0550x over previous
//
#include <hip/hip_runtime.h>
#include <math.h>

#define N_NODES 100000
#define N_EDGES 1600000
#define IN_DIM  512
#define OUT_DIM 128

// ---------------- ws layout (float offsets) ----------------
#define OFF_S1    0        // 512  (s1 | s2 contiguous: 1024 floats)
#define OFF_S2    512      // 512
#define OFF_M     1024     // 256: m[2][128]
#define OFF_U     1280     // 256: u[2][128]
#define OFF_WV    1536     // 1024: w12[512] | w21[512]
#define OFF_ALPHA 2560     // 2
#define OFF_PA    4096     // float2[N]: {p_f2, p_s2}   (graph2 table)
#define OFF_PB    204096   // float2[N]: {p_f1, p_s1}   (graph1 table)
#define OFF_DEGR  404096   // int[2][100000] reduced degrees
#define OFF_BUF   604096   // degbuf: Cd*200000 ints -> dead after k_degred, then
                           // pbuf: 1024*1024 floats (aliases degbuf) -> dead after k_sred
                           // scbuf: Cs*400000 floats at OFF_BUF + Cd*200000

// 32 KiB LDS partitions -> up to 5 blocks/CU (512 thr each)
#define P_SC   4096        // nodes per scatter partition (2 * 4096 * 4B = 32KB LDS)
#define NP_SC  25          // ceil(100000/4096)
#define P_D    8192        // nodes per degree partition (8192 * 4B = 32KB LDS)
#define NP_D   13          // ceil(100000/8192)
#define WSUM_NBLK 1024
#define CS_MAX 20          // k_sc_b grid = 25*20*2 = 1000 blocks (~3.9/CU)
#define CD_MAX 32          // k_deg_b grid = 13*32*2 = 832 blocks (~3.25/CU)

// bijective hardware-block -> logical-id swizzle: blocks with the same
// hardware residue mod 8 (= same XCD under round-robin dispatch) get a
// CONTIGUOUS logical range, so logically-adjacent blocks share an XCD's L2.
__device__ __forceinline__ int xcd_swz(int bx, int nwg) {
    const int q = nwg >> 3, r = nwg & 7;
    const int x = bx & 7, i = bx >> 3;
    return (x < r ? x * (q + 1) : r * (q + 1) + (x - r) * q) + i;
}

__global__ void k_zero(float* __restrict__ p, long n) {
    long i = (long)blockIdx.x * blockDim.x + threadIdx.x;
    long stride = (long)gridDim.x * blockDim.x;
    for (long j = i; j < n; j += stride) p[j] = 0.0f;
}

// ---- binned degree histogram: 1-D grid NP_D*Cd*2, 512 thr, 32KB LDS, no global atomics.
// Swizzled so all NP_D partition blocks of one (g,c) edge-chunk live on one XCD.
// Block 0 also zeroes the s1/s2/m accumulators (folded k_zero).
__global__ __launch_bounds__(512) void k_deg_b(const int* __restrict__ src1,
                                               const int* __restrict__ src2,
                                               int* __restrict__ degbuf, int Cd,
                                               float* __restrict__ wsf) {
    __shared__ int bins[P_D];
    const int nwg  = NP_D * Cd * 2;
    const int l    = xcd_swz(blockIdx.x, nwg);
    const int part = l % NP_D;
    const int grp  = l / NP_D;        // g*Cd + c
    const int c    = grp % Cd;
    const int g    = grp / Cd;
    const int tid  = threadIdx.x;
    const int base = part * P_D;
    if (blockIdx.x == 0) {            // fold k_zero: s1,s2,m accumulators
        for (int i = tid; i < 1280; i += 512) wsf[i] = 0.0f;
    }
    const int4* srcv = (const int4*)(g ? src2 : src1);
    for (int i = tid; i < P_D; i += 512) bins[i] = 0;
    __syncthreads();
    const long E4 = N_EDGES / 4;
    const long s4 = ((long)c * E4) / Cd;
    const long e4 = ((long)(c + 1) * E4) / Cd;
    long i = s4 + tid;
    if (i < e4) {
        int4 s = srcv[i];
        for (;;) {
            const long inext = i + 512;
            int4 cur = s;
            if (inext < e4) s = srcv[inext];          // prefetch next int4
            unsigned l0 = (unsigned)(cur.x - base), l1 = (unsigned)(cur.y - base);
            unsigned l2 = (unsigned)(cur.z - base), l3 = (unsigned)(cur.w - base);
            if (l0 < P_D) atomicAdd(&bins[l0], 1);
            if (l1 < P_D) atomicAdd(&bins[l1], 1);
            if (l2 < P_D) atomicAdd(&bins[l2], 1);
            if (l3 < P_D) atomicAdd(&bins[l3], 1);
            i = inext;
            if (i >= e4) break;
        }
    }
    __syncthreads();
    const int valid = min(P_D, N_NODES - base);
    int* o = degbuf + (size_t)c * 200000 + (size_t)g * 100000 + base;
    for (int li = tid; li < valid; li += 512) o[li] = bins[li];
}

__global__ void k_degred(const int* __restrict__ degbuf, int* __restrict__ degr, int Cd) {
    int j = blockIdx.x * blockDim.x + threadIdx.x;
    if (j < 200000) {
        int acc = 0;
        for (int c = 0; c < Cd; ++c) acc += degbuf[(size_t)c * 200000 + j];
        degr[j] = acc;
    }
}

// ---- partial-sum wsum: contiguous chunks, 4-row unroll, plain float4 stores.
// Block b writes pbuf[b*1024 + 0..511] = sum deg1[v]*feat[v][:], [512..1023] for deg2.
__global__ __launch_bounds__(128) void k_wsum_p(const float* __restrict__ feat,
                                                const int* __restrict__ degr,
                                                float* __restrict__ pbuf) {
    const int t = threadIdx.x;
    const int k = 4 * t;
    const int chunk = (N_NODES + WSUM_NBLK - 1) / WSUM_NBLK;   // 98
    const int v0 = blockIdx.x * chunk;
    const int v1 = min(v0 + chunk, N_NODES);
    float4 a1 = {0.f, 0.f, 0.f, 0.f};
    float4 a2 = {0.f, 0.f, 0.f, 0.f};
    const float* fp = feat + (size_t)v0 * IN_DIM + k;
    int v = v0;
    for (; v + 4 <= v1; v += 4, fp += 4 * IN_DIM) {
        float4 f0 = *(const float4*)(fp);
        float4 f1 = *(const float4*)(fp + IN_DIM);
        float4 f2 = *(const float4*)(fp + 2 * IN_DIM);
        float4 f3 = *(const float4*)(fp + 3 * IN_DIM);
        float d10 = (float)degr[v],     d20 = (float)degr[100000 + v];
        float d11 = (float)degr[v + 1], d21 = (float)degr[100000 + v + 1];
        float d12 = (float)degr[v + 2], d22 = (float)degr[100000 + v + 2];
        float d13 = (float)degr[v + 3], d23 = (float)degr[100000 + v + 3];
        a1.x += d10 * f0.x + d11 * f1.x + d12 * f2.x + d13 * f3.x;
        a1.y += d10 * f0.y + d11 * f1.y + d12 * f2.y + d13 * f3.y;
        a1.z += d10 * f0.z + d11 * f1.z + d12 * f2.z + d13 * f3.z;
        a1.w += d10 * f0.w + d11 * f1.w + d12 * f2.w + d13 * f3.w;
        a2.x += d20 * f0.x + d21 * f1.x + d22 * f2.x + d23 * f3.x;
        a2.y += d20 * f0.y + d21 * f1.y + d22 * f2.y + d23 * f3.y;
        a2.z += d20 * f0.z + d21 * f1.z + d22 * f2.z + d23 * f3.z;
        a2.w += d20 * f0.w + d21 * f1.w + d22 * f2.w + d23 * f3.w;
    }
    for (; v < v1; ++v, fp += IN_DIM) {
        float4 f = *(const float4*)(fp);
        float d1 = (float)degr[v], d2 = (float)degr[100000 + v];
        a1.x += d1 * f.x; a1.y += d1 * f.y; a1.z += d1 * f.z; a1.w += d1 * f.w;
        a2.x += d2 * f.x; a2.y += d2 * f.y; a2.z += d2 * f.z; a2.w += d2 * f.w;
    }
    float* o = pbuf + (size_t)blockIdx.x * 1024;
    *(float4*)(o + k) = a1;           // zeros for empty blocks (pbuf is poisoned!)
    *(float4*)(o + 512 + k) = a2;
}

// grid (4,16) x 256: dim d = bx*256+t; sum 64 block-partials; 16-deep atomic chain only.
__global__ void k_sred(const float* __restrict__ pbuf, float* __restrict__ s) {
    const int d = blockIdx.x * 256 + threadIdx.x;
    const int b0 = blockIdx.y * 64;
    float acc = 0.f;
#pragma unroll 8
    for (int b = 0; b < 64; ++b) acc += pbuf[(size_t)(b0 + b) * 1024 + d];
    atomicAdd(&s[d], acc);
}

__global__ void k_gemv_m(const float* __restrict__ ws, const float* __restrict__ W1,
                         const float* __restrict__ W2, float* __restrict__ m) {
    const int mat = blockIdx.y;
    const float* W = mat ? W2 : W1;
    const float* s = ws + (mat ? OFF_S2 : OFF_S1);
    const int t = threadIdx.x;
    const int k0 = blockIdx.x * 32;
    float acc = 0.f;
#pragma unroll 8
    for (int j = 0; j < 32; ++j)
        acc += s[k0 + j] * W[(k0 + j) * OUT_DIM + t];
    atomicAdd(&m[mat * OUT_DIM + t], acc);
}

__global__ void k_u(float* __restrict__ ws, const float* __restrict__ b1,
                    const float* __restrict__ b2, const float* __restrict__ Wb,
                    const float* __restrict__ bb) {
    __shared__ float c[OUT_DIM];
    __shared__ float red[128];
    const int mat = blockIdx.x;
    const int t = threadIdx.x;
    const float* b = mat ? b2 : b1;
    float mv = ws[OFF_M + mat * OUT_DIM + t] * (1.0f / N_NODES) + b[t];
    c[t] = 1.0f / (1.0f + expf(-mv));
    __syncthreads();
    float acc = 0.f;
    const float4* wr = (const float4*)(Wb + t * OUT_DIM);
#pragma unroll 8
    for (int j = 0; j < OUT_DIM / 4; ++j) {
        float4 w = wr[j];
        acc += w.x * c[4 * j] + w.y * c[4 * j + 1] + w.z * c[4 * j + 2] + w.w * c[4 * j + 3];
    }
    ws[OFF_U + mat * OUT_DIM + t] = acc;   // mat0: u1, mat1: u2
    const float* bo = mat ? b1 : b2;       // alpha0 = b2.u1+bb ; alpha1 = b1.u2+bb
    red[t] = bo[t] * acc;
    __syncthreads();
    for (int s = 64; s > 0; s >>= 1) {
        if (t < s) red[t] += red[t + s];
        __syncthreads();
    }
    if (t == 0) ws[OFF_ALPHA + mat] = red[0] + bb[0];
}

__global__ void k_w(const float* __restrict__ ws, const float* __restrict__ W1,
                    const float* __restrict__ W2, float* __restrict__ wv) {
    const int wid = (blockIdx.x * blockDim.x + threadIdx.x) >> 6;
    const int lane = threadIdx.x & 63;
    const int mat = wid >> 9;
    const int k = wid & 511;
    const float* W = mat ? W2 : W1;
    const float* u = ws + OFF_U + (mat ? 0 : OUT_DIM);  // mat0 needs u2, mat1 needs u1
    float2 w = *(const float2*)(W + k * OUT_DIM + 2 * lane);
    float2 uu = *(const float2*)(u + 2 * lane);
    float acc = w.x * uu.x + w.y * uu.y;
#pragma unroll
    for (int off = 32; off > 0; off >>= 1) acc += __shfl_down(acc, off);
    if (lane == 0) wv[mat * IN_DIM + k] = acc;
}

__device__ __forceinline__ float dot8(float4 a, float4 b, float4 wa, float4 wb) {
    return a.x * wa.x + a.y * wa.y + a.z * wa.z + a.w * wa.w
         + b.x * wb.x + b.y * wb.y + b.z * wb.z + b.w * wb.w;
}

__global__ void k_proj(const float* __restrict__ feat, const float* __restrict__ shuf,
                       const float* __restrict__ ws, float2* __restrict__ pA,
                       float2* __restrict__ pB) {
    const int lane = threadIdx.x & 63;
    const int gw = (blockIdx.x * blockDim.x + threadIdx.x) >> 6;
    const int nw = (gridDim.x * blockDim.x) >> 6;
    const int kA = 4 * lane;
    const int kB = 256 + 4 * lane;
    const float* wv = ws + OFF_WV;
    const float4 w12a = *(const float4*)(wv + kA);
    const float4 w12b = *(const float4*)(wv + kB);
    const float4 w21a = *(const float4*)(wv + IN_DIM + kA);
    const float4 w21b = *(const float4*)(wv + IN_DIM + kB);
    for (int v = gw; v < N_NODES; v += nw) {
        const float* rf = feat + (size_t)v * IN_DIM;
        float4 fa = *(const float4*)(rf + kA);
        float4 fb = *(const float4*)(rf + kB);
        const float* rs = shuf + (size_t)v * IN_DIM;
        float4 sa = *(const float4*)(rs + kA);
        float4 sb = *(const float4*)(rs + kB);
        float d12f = dot8(fa, fb, w12a, w12b);
        float d21f = dot8(fa, fb, w21a, w21b);
        float d12s = dot8(sa, sb, w12a, w12b);
        float d21s = dot8(sa, sb, w21a, w21b);
#pragma unroll
        for (int off = 32; off > 0; off >>= 1) {
            d12f += __shfl_down(d12f, off);
            d21f += __shfl_down(d21f, off);
            d12s += __shfl_down(d12s, off);
            d21s += __shfl_down(d21s, off);
        }
        if (lane == 0) {
            pA[v] = make_float2(d21f, d21s);   // {p_f2, p_s2}
            pB[v] = make_float2(d12f, d12s);   // {p_f1, p_s1}
        }
    }
}

// ---- binned scatter: 1-D grid NP_SC*Cs*2, 512 thr, 32KB LDS, no global atomics.
// Swizzled so all NP_SC partition blocks of one (g,c) edge-chunk live on one XCD:
// dst/src chunk and the 800KB gather table are L2-resident (per-XCD working set
// at Cs=20: 5 chunks x 640KB + 800KB table ~ 4MB = L2).
__global__ __launch_bounds__(512) void k_sc_b(const int* __restrict__ src1,
                                              const int* __restrict__ dst1,
                                              const int* __restrict__ src2,
                                              const int* __restrict__ dst2,
                                              const float2* __restrict__ pA,
                                              const float2* __restrict__ pB,
                                              float* __restrict__ scbuf, int Cs) {
    __shared__ float bins[2 * P_SC];
    const int nwg  = NP_SC * Cs * 2;
    const int l    = xcd_swz(blockIdx.x, nwg);
    const int part = l % NP_SC;
    const int grp  = l / NP_SC;       // g*Cs + c
    const int c    = grp % Cs;
    const int g    = grp / Cs;
    const int tid  = threadIdx.x;
    const int base = part * P_SC;
    const int4* dstv = (const int4*)(g ? dst2 : dst1);
    const int4* srcv = (const int4*)(g ? src2 : src1);
    const float2* tab = g ? pA : pB;
    for (int i = tid; i < 2 * P_SC; i += 512) bins[i] = 0.f;
    __syncthreads();
    const long E4 = N_EDGES / 4;
    const long s4 = ((long)c * E4) / Cs;
    const long e4 = ((long)(c + 1) * E4) / Cs;
    long i = s4 + tid;
    if (i < e4) {
        int4 d = dstv[i];
        for (;;) {
            const long inext = i + 512;
            int4 cur = d;
            if (inext < e4) d = dstv[inext];          // prefetch next int4
            unsigned l0 = (unsigned)(cur.x - base), l1 = (unsigned)(cur.y - base);
            unsigned l2 = (unsigned)(cur.z - base), l3 = (unsigned)(cur.w - base);
            bool h0 = l0 < P_SC, h1 = l1 < P_SC, h2 = l2 < P_SC, h3 = l3 < P_SC;
            if (h0 | h1 | h2 | h3) {
                int4 s = srcv[i];
                if (h0) { float2 p = tab[s.x]; atomicAdd(&bins[l0], p.x); atomicAdd(&bins[P_SC + l0], p.y); }
                if (h1) { float2 p = tab[s.y]; atomicAdd(&bins[l1], p.x); atomicAdd(&bins[P_SC + l1], p.y); }
                if (h2) { float2 p = tab[s.z]; atomicAdd(&bins[l2], p.x); atomicAdd(&bins[P_SC + l2], p.y); }
                if (h3) { float2 p = tab[s.w]; atomicAdd(&bins[l3], p.x); atomicAdd(&bins[P_SC + l3], p.y); }
            }
            i = inext;
            if (i >= e4) break;
        }
    }
    __syncthreads();
    const int valid = min(P_SC, N_NODES - base);
    const int secA = g ? 0 : 1;
    const int secB = g ? 2 : 3;
    float* oA = scbuf + ((size_t)c * 4 + secA) * 100000 + base;
    float* oB = scbuf + ((size_t)c * 4 + secB) * 100000 + base;
    for (int li = tid; li < valid; li += 512) {
        oA[li] = bins[li];
        oB[li] = bins[P_SC + li];
    }
}

__global__ void k_final(const float* __restrict__ scbuf, const float* __restrict__ ws,
                        float* __restrict__ out, int Cs) {
    int i = blockIdx.x * blockDim.x + threadIdx.x;
    if (i < 4 * N_NODES) {
        int sec = i / N_NODES;
        int v = i - sec * N_NODES;
        float t = 0.f;
        for (int c = 0; c < Cs; ++c) t += scbuf[((size_t)c * 4 + sec) * 100000 + v];
        out[i] = ws[OFF_ALPHA + (sec & 1)] + t;
    }
}

// ---------------- fallbacks (small ws) ----------------
__global__ void k_wsum_atomic(const float* __restrict__ feat, const int* __restrict__ degr,
                              float* __restrict__ s1, float* __restrict__ s2) {
    const int k = 4 * threadIdx.x;
    float4 a1 = {0.f, 0.f, 0.f, 0.f};
    float4 a2 = {0.f, 0.f, 0.f, 0.f};
    for (int v = blockIdx.x; v < N_NODES; v += gridDim.x) {
        float d1 = (float)degr[v];
        float d2 = (float)degr[100000 + v];
        float4 f = *reinterpret_cast<const float4*>(feat + (size_t)v * IN_DIM + k);
        a1.x += d1 * f.x; a1.y += d1 * f.y; a1.z += d1 * f.z; a1.w += d1 * f.w;
        a2.x += d2 * f.x; a2.y += d2 * f.y; a2.z += d2 * f.z; a2.w += d2 * f.w;
    }
    atomicAdd(&s1[k],     a1.x); atomicAdd(&s1[k + 1], a1.y);
    atomicAdd(&s1[k + 2], a1.z); atomicAdd(&s1[k + 3], a1.w);
    atomicAdd(&s2[k],     a2.x); atomicAdd(&s2[k + 1], a2.y);
    atomicAdd(&s2[k + 2], a2.z); atomicAdd(&s2[k + 3], a2.w);
}

__global__ void k_deg_direct(const int* __restrict__ src1, const int* __restrict__ src2,
                             int* __restrict__ degr) {
    int i = blockIdx.x * blockDim.x + threadIdx.x;
    if (i < N_EDGES) {
        atomicAdd(&degr[src1[i]], 1);
        atomicAdd(&degr[100000 + src2[i]], 1);
    }
}

__global__ void k_init(float* __restrict__ out, const float* __restrict__ ws) {
    int i = blockIdx.x * blockDim.x + threadIdx.x;
    if (i < 4 * N_NODES) {
        int sec = i / N_NODES;
        out[i] = ws[OFF_ALPHA + (sec & 1)];
    }
}

__global__ void k_scatter_direct(const int* __restrict__ src1, const int* __restrict__ dst1,
                                 const int* __restrict__ src2, const int* __restrict__ dst2,
                                 const float2* __restrict__ pA, const float2* __restrict__ pB,
                                 float* __restrict__ out) {
    int i = blockIdx.x * blockDim.x + threadIdx.x;
    if (i < N_EDGES) {
        int s1 = src1[i], d1 = dst1[i];
        int s2 = src2[i], d2 = dst2[i];
        float2 a = pA[s2];
        float2 b = pB[s1];
        atomicAdd(&out[d2],                 a.x);
        atomicAdd(&out[2 * N_NODES + d2],   a.y);
        atomicAdd(&out[N_NODES + d1],       b.x);
        atomicAdd(&out[3 * N_NODES + d1],   b.y);
    }
}

extern "C" void kernel_launch(void* const* d_in, const int* in_sizes, int n_in,
                              void* d_out, int out_size, void* d_ws, size_t ws_size,
                              hipStream_t stream) {
    const float* feat = (const float*)d_in[0];
    const float* shuf = (const float*)d_in[1];
    const int* src1 = (const int*)d_in[2];
    const int* dst1 = (const int*)d_in[3];
    const int* src2 = (const int*)d_in[4];
    const int* dst2 = (const int*)d_in[5];
    const float* W1 = (const float*)d_in[6];
    const float* b1 = (const float*)d_in[7];
    const float* W2 = (const float*)d_in[8];
    const float* b2 = (const float*)d_in[9];
    const float* Wb = (const float*)d_in[10];
    const float* bb = (const float*)d_in[11];
    float* out = (float*)d_out;

    float* wsf = (float*)d_ws;
    float2* pA = (float2*)(wsf + OFF_PA);
    float2* pB = (float2*)(wsf + OFF_PB);
    int* degr = (int*)(wsf + OFF_DEGR);

    long availf = (long)(ws_size / 4);
    long budget = availf - OFF_BUF;
    int Cd = 0, Cs = 0;
    if (budget >= 600000) {
        Cs = (int)((budget / 2) / 400000); if (Cs > CS_MAX) Cs = CS_MAX; if (Cs < 1) Cs = 1;
        Cd = (int)((budget - (long)Cs * 400000) / 200000); if (Cd > CD_MAX) Cd = CD_MAX; if (Cd < 1) Cd = 1;
    }
    const bool pb_ok = (budget >= 1048576);   // pbuf aliases the (dead) degbuf region

    if (Cd >= 1) {
        int* degbuf = (int*)(wsf + OFF_BUF);
        float* pbuf = wsf + OFF_BUF;          // alias: degbuf dead after k_degred
        float* scbuf = wsf + OFF_BUF + (long)Cd * 200000;
        k_deg_b<<<NP_D * Cd * 2, 512, 0, stream>>>(src1, src2, degbuf, Cd, wsf);
        k_degred<<<(200000 + 255) / 256, 256, 0, stream>>>(degbuf, degr, Cd);
        if (pb_ok) {
            k_wsum_p<<<WSUM_NBLK, 128, 0, stream>>>(feat, degr, pbuf);
            k_sred<<<dim3(4, 16), 256, 0, stream>>>(pbuf, wsf + OFF_S1);
        } else {
            k_wsum_atomic<<<2048, 128, 0, stream>>>(feat, degr, wsf + OFF_S1, wsf + OFF_S2);
        }
        k_gemv_m<<<dim3(16, 2), 128, 0, stream>>>(wsf, W1, W2, wsf + OFF_M);
        k_u<<<2, 128, 0, stream>>>(wsf, b1, b2, Wb, bb);
        k_w<<<256, 256, 0, stream>>>(wsf, W1, W2, wsf + OFF_WV);
        k_proj<<<8192, 256, 0, stream>>>(feat, shuf, wsf, pA, pB);
        k_sc_b<<<NP_SC * Cs * 2, 512, 0, stream>>>(src1, dst1, src2, dst2, pA, pB, scbuf, Cs);
        k_final<<<(4 * N_NODES + 255) / 256, 256, 0, stream>>>(scbuf, wsf, out, Cs);
    } else {
        k_zero<<<2, 512, 0, stream>>>(wsf, 1280);
        k_zero<<<256, 256, 0, stream>>>((float*)degr, 200000);
        k_deg_direct<<<(N_EDGES + 255) / 256, 256, 0, stream>>>(src1, src2, degr);
        k_wsum_atomic<<<2048, 128, 0, stream>>>(feat, degr, wsf + OFF_S1, wsf + OFF_S2);
        k_gemv_m<<<dim3(16, 2), 128, 0, stream>>>(wsf, W1, W2, wsf + OFF_M);
        k_u<<<2, 128, 0, stream>>>(wsf, b1, b2, Wb, bb);
        k_w<<<256, 256, 0, stream>>>(wsf, W1, W2, wsf + OFF_WV);
        k_proj<<<8192, 256, 0, stream>>>(feat, shuf, wsf, pA, pB);
        k_init<<<(4 * N_NODES + 255) / 256, 256, 0, stream>>>(out, wsf);
        k_scatter_direct<<<(N_EDGES + 255) / 256, 256, 0, stream>>>(src1, dst1, src2, dst2, pA, pB, out);
    }
}